// Round 1
// baseline (1118.778 us; speedup 1.0000x reference)
//
#include <hip/hip_runtime.h>
#include <hip/hip_bf16.h>
#include <cstdint>
#include <cstddef>

// Problem constants
#define NROWS 32768
#define DDIM  4096
#define HDIM  256
#define ODIM  64

// ws layout (in ushort/bf16 elements):
//   [0)          w1 swizzled, 2 paths x 4096*256        (2 * 1048576)
//   [2097152)    w2 swizzled, 2 paths x 256*64           (2 * 16384)
//   [2129920)    h = relu(x@w1+b1), 2 paths x 32768*256  (2 * 8388608)
#define OFF_W2    2097152
#define OFF_H     2129920
#define W1_STRIDE 1048576
#define W2_STRIDE 16384
#define H_STRIDE  8388608

typedef short bf16x8 __attribute__((ext_vector_type(8)));
typedef float f32x4  __attribute__((ext_vector_type(4)));

__device__ __forceinline__ unsigned short f2bf(float f) {
    unsigned int u = __builtin_bit_cast(unsigned int, f);
    u += 0x7fffu + ((u >> 16) & 1u);   // RNE
    return (unsigned short)(u >> 16);
}

// ---------------------------------------------------------------------------
// prep: w1 [4096][256] fp32 -> bf16 swizzled [kt=64][kb=8][n=256][j=8]
//       w2 [256][64]  fp32 -> bf16 swizzled [kb=32][n=64][j=8]
// ---------------------------------------------------------------------------
__global__ __launch_bounds__(256) void prep_kernel(
    const float* __restrict__ w1u, const float* __restrict__ w1i,
    const float* __restrict__ w2u, const float* __restrict__ w2i,
    unsigned short* __restrict__ ws)
{
    int idx = blockIdx.x * 256 + threadIdx.x;
    if (idx < 2 * DDIM * HDIM) {
        int p = idx >> 20;          // 4096*256 = 2^20
        int e = idx & 1048575;
        int k = e >> 8;             // 0..4095
        int n = e & 255;
        const float* src = p ? w1i : w1u;
        float v = src[e];           // row-major [D][H]
        int kt  = k >> 6;
        int kbl = (k >> 3) & 7;
        int j   = k & 7;
        int dst = ((kt * 8 + kbl) * 256 + n) * 8 + j;
        ws[p * W1_STRIDE + dst] = f2bf(v);
    } else {
        int e2 = idx - 2 * DDIM * HDIM;   // 0..32767
        int p  = e2 >> 14;
        int e  = e2 & 16383;
        int k  = e >> 6;            // 0..255
        int n  = e & 63;
        const float* src = p ? w2i : w2u;
        float v = src[e];           // row-major [H][O]
        int dst = ((k >> 3) * 64 + n) * 8 + (k & 7);
        ws[OFF_W2 + p * W2_STRIDE + dst] = f2bf(v);
    }
}

// ---------------------------------------------------------------------------
// gemm1: h = relu(x @ w1 + b1), bf16 MFMA.
// grid: 1024 blocks (512 row-blocks x 2 paths), 256 threads (4 waves).
// Block tile: 64 rows x 256 cols, BK=64. Wave w: cols w*64..w*64+63.
// LDS: x_lds [kb=8][row=64][8] bf16 (8 KB), w_lds [kb=8][n=256][8] bf16 (32 KB)
// ---------------------------------------------------------------------------
__global__ __launch_bounds__(256, 3) void gemm1_kernel(
    const float* __restrict__ xu, const float* __restrict__ xi,
    const float* __restrict__ b1u, const float* __restrict__ b1i,
    const unsigned short* __restrict__ w1_base,
    unsigned short* __restrict__ h_base)
{
    __shared__ unsigned short xls[8 * 64 * 8];    //  8 KB
    __shared__ unsigned short wls[8 * 256 * 8];   // 32 KB

    const int t    = threadIdx.x;
    const int lane = t & 63;
    const int w    = t >> 6;            // wave id = col-block
    const int path = blockIdx.x & 1;
    const int rb   = blockIdx.x >> 1;   // 0..511

    const float* x  = path ? xi : xu;
    const float* b1 = path ? b1i : b1u;
    const unsigned short* wsw = w1_base + path * W1_STRIDE;
    unsigned short* hp = h_base + path * H_STRIDE;

    // x staging assignment: thread t covers (row_local = t&63, chunk c = t>>6)
    const int row_local = t & 63;
    const int cpart     = t >> 6;
    const float* xp = x + (size_t)(rb * 64 + row_local) * DDIM + cpart * 16;

    f32x4 acc[4][4];
    #pragma unroll
    for (int mt = 0; mt < 4; ++mt)
        #pragma unroll
        for (int nt = 0; nt < 4; ++nt)
            acc[mt][nt] = (f32x4){0.f, 0.f, 0.f, 0.f};

    const int m15 = lane & 15;
    const int q   = lane >> 4;

    for (int kt = 0; kt < 64; ++kt) {
        // ---- global fp32 x -> regs -> bf16 (no LDS touched yet) ----
        f32x4 v0 = ((const f32x4*)xp)[0];
        f32x4 v1 = ((const f32x4*)xp)[1];
        f32x4 v2 = ((const f32x4*)xp)[2];
        f32x4 v3 = ((const f32x4*)xp)[3];
        xp += 64;
        bf16x8 p0, p1;
        p0[0] = (short)f2bf(v0[0]); p0[1] = (short)f2bf(v0[1]);
        p0[2] = (short)f2bf(v0[2]); p0[3] = (short)f2bf(v0[3]);
        p0[4] = (short)f2bf(v1[0]); p0[5] = (short)f2bf(v1[1]);
        p0[6] = (short)f2bf(v1[2]); p0[7] = (short)f2bf(v1[3]);
        p1[0] = (short)f2bf(v2[0]); p1[1] = (short)f2bf(v2[1]);
        p1[2] = (short)f2bf(v2[2]); p1[3] = (short)f2bf(v2[3]);
        p1[4] = (short)f2bf(v3[0]); p1[5] = (short)f2bf(v3[1]);
        p1[6] = (short)f2bf(v3[2]); p1[7] = (short)f2bf(v3[3]);

        __syncthreads();   // previous iteration's LDS reads done

        // ---- stage x tile (contiguous per-wave ds_write_b128) ----
        *(bf16x8*)&xls[(2 * cpart    ) * 512 + row_local * 8] = p0;
        *(bf16x8*)&xls[(2 * cpart + 1) * 512 + row_local * 8] = p1;

        // ---- stage w tile via async global->LDS DMA, width 16 ----
        const unsigned short* wsrc = wsw + kt * 16384 + t * 8;
        #pragma unroll
        for (int j = 0; j < 8; ++j) {
            __builtin_amdgcn_global_load_lds(
                (const __attribute__((address_space(1))) unsigned int*)(wsrc + j * 2048),
                (__attribute__((address_space(3))) unsigned int*)
                    ((char*)wls + (t & 192) * 16 + j * 4096),
                16, 0, 0);
        }

        __syncthreads();   // staging complete (vmcnt+lgkm drained)

        // ---- compute: 2 k-steps of 32, 16 MFMA each ----
        #pragma unroll
        for (int ks = 0; ks < 2; ++ks) {
            const int kbq = ks * 4 + q;
            bf16x8 a[4], b[4];
            #pragma unroll
            for (int mt = 0; mt < 4; ++mt)
                a[mt] = *(const bf16x8*)&xls[kbq * 512 + (mt * 16 + m15) * 8];
            #pragma unroll
            for (int nt = 0; nt < 4; ++nt)
                b[nt] = *(const bf16x8*)&wls[kbq * 2048 + (w * 64 + nt * 16 + m15) * 8];
            #pragma unroll
            for (int mt = 0; mt < 4; ++mt)
                #pragma unroll
                for (int nt = 0; nt < 4; ++nt)
                    acc[mt][nt] = __builtin_amdgcn_mfma_f32_16x16x32_bf16(
                        a[mt], b[nt], acc[mt][nt], 0, 0, 0);
        }
    }

    // ---- epilogue: +b1, relu, bf16 store (h row-major [32768][256]) ----
    float b1v[4];
    #pragma unroll
    for (int nt = 0; nt < 4; ++nt)
        b1v[nt] = b1[w * 64 + nt * 16 + m15];

    #pragma unroll
    for (int mt = 0; mt < 4; ++mt) {
        const int row = rb * 64 + mt * 16 + q * 4;
        #pragma unroll
        for (int nt = 0; nt < 4; ++nt) {
            const int col = w * 64 + nt * 16 + m15;
            #pragma unroll
            for (int r = 0; r < 4; ++r) {
                float v = acc[mt][nt][r] + b1v[nt];
                v = fmaxf(v, 0.0f);
                hp[(size_t)(row + r) * HDIM + col] = f2bf(v);
            }
        }
    }
}

// ---------------------------------------------------------------------------
// final: u = h_u @ w2u + b2u ; v = h_i @ w2i + b2i ; out = sigmoid(dot(u,v))
// grid: 512 blocks x 256 threads (4 waves, 16 rows/wave). No LDS.
// A-frags loaded straight from global h (8 consecutive bf16 per lane).
// ---------------------------------------------------------------------------
__global__ __launch_bounds__(256) void final_kernel(
    const unsigned short* __restrict__ h_base,
    const unsigned short* __restrict__ w2_base,
    const float* __restrict__ b2u, const float* __restrict__ b2i,
    float* __restrict__ out)
{
    const int t    = threadIdx.x;
    const int lane = t & 63;
    const int w    = t >> 6;
    const int r0   = blockIdx.x * 64 + w * 16;
    const int m15  = lane & 15;
    const int q    = lane >> 4;

    f32x4 uacc[4], vacc[4];

    for (int path = 0; path < 2; ++path) {
        const unsigned short* h  = h_base  + path * H_STRIDE;
        const unsigned short* w2 = w2_base + path * W2_STRIDE;
        const float* b2 = path ? b2i : b2u;

        f32x4 acc[4];
        #pragma unroll
        for (int nt = 0; nt < 4; ++nt) acc[nt] = (f32x4){0.f, 0.f, 0.f, 0.f};

        #pragma unroll
        for (int ks = 0; ks < 8; ++ks) {
            const int kb = ks * 4 + q;
            bf16x8 a = *(const bf16x8*)&h[(size_t)(r0 + m15) * HDIM + kb * 8];
            #pragma unroll
            for (int nt = 0; nt < 4; ++nt) {
                bf16x8 b = *(const bf16x8*)&w2[(kb * 64 + nt * 16 + m15) * 8];
                acc[nt] = __builtin_amdgcn_mfma_f32_16x16x32_bf16(a, b, acc[nt], 0, 0, 0);
            }
        }
        #pragma unroll
        for (int nt = 0; nt < 4; ++nt) {
            const float bb = b2[nt * 16 + m15];
            #pragma unroll
            for (int r = 0; r < 4; ++r) acc[nt][r] += bb;
            if (path == 0) uacc[nt] = acc[nt]; else vacc[nt] = acc[nt];
        }
    }

    #pragma unroll
    for (int r = 0; r < 4; ++r) {
        float p = uacc[0][r] * vacc[0][r] + uacc[1][r] * vacc[1][r]
                + uacc[2][r] * vacc[2][r] + uacc[3][r] * vacc[3][r];
        p += __shfl_xor(p, 1);
        p += __shfl_xor(p, 2);
        p += __shfl_xor(p, 4);
        p += __shfl_xor(p, 8);
        if (m15 == 0)
            out[r0 + q * 4 + r] = 1.0f / (1.0f + __expf(-p));
    }
}

// ---------------------------------------------------------------------------
extern "C" void kernel_launch(void* const* d_in, const int* in_sizes, int n_in,
                              void* d_out, int out_size, void* d_ws, size_t ws_size,
                              hipStream_t stream)
{
    const float* xu  = (const float*)d_in[0];
    const float* xi  = (const float*)d_in[1];
    const float* w1u = (const float*)d_in[2];
    const float* b1u = (const float*)d_in[3];
    const float* w2u = (const float*)d_in[4];
    const float* b2u = (const float*)d_in[5];
    const float* w1i = (const float*)d_in[6];
    const float* b1i = (const float*)d_in[7];
    const float* w2i = (const float*)d_in[8];
    const float* b2i = (const float*)d_in[9];

    unsigned short* ws = (unsigned short*)d_ws;
    float* out = (float*)d_out;

    // 2*4096*256 + 2*256*64 = 2129920 elements to convert
    prep_kernel<<<8320, 256, 0, stream>>>(w1u, w1i, w2u, w2i, ws);

    gemm1_kernel<<<1024, 256, 0, stream>>>(xu, xi, b1u, b1i,
                                           ws, ws + OFF_H);

    final_kernel<<<512, 256, 0, stream>>>(ws + OFF_H, ws + OFF_W2,
                                          b2u, b2i, out);
}

// Round 2
// 1081.945 us; speedup vs baseline: 1.0340x; 1.0340x over previous
//
#include <hip/hip_runtime.h>
#include <hip/hip_bf16.h>
#include <cstdint>
#include <cstddef>

// Problem constants
#define NROWS 32768
#define DDIM  4096
#define HDIM  256
#define ODIM  64

// ws layout (in ushort/bf16 elements):
//   [0)          w1 swizzled, 2 paths x 4096*256        (2 * 1048576)
//   [2097152)    w2 swizzled, 2 paths x 256*64           (2 * 16384)
//   [2129920)    h = relu(x@w1+b1), 2 paths x 32768*256  (2 * 8388608)
#define OFF_W2    2097152
#define OFF_H     2129920
#define W1_STRIDE 1048576
#define W2_STRIDE 16384
#define H_STRIDE  8388608

typedef short bf16x8 __attribute__((ext_vector_type(8)));
typedef float f32x4  __attribute__((ext_vector_type(4)));

__device__ __forceinline__ unsigned short f2bf(float f) {
    unsigned int u = __builtin_bit_cast(unsigned int, f);
    u += 0x7fffu + ((u >> 16) & 1u);   // RNE
    return (unsigned short)(u >> 16);
}

// ---------------------------------------------------------------------------
// prep: w1 [4096][256] fp32 -> bf16 swizzled [kt=64][kb=8][n=256][j=8]
//       w2 [256][64]  fp32 -> bf16 swizzled [kb=32][n=64][j=8]
// ---------------------------------------------------------------------------
__global__ __launch_bounds__(256) void prep_kernel(
    const float* __restrict__ w1u, const float* __restrict__ w1i,
    const float* __restrict__ w2u, const float* __restrict__ w2i,
    unsigned short* __restrict__ ws)
{
    int idx = blockIdx.x * 256 + threadIdx.x;
    if (idx < 2 * DDIM * HDIM) {
        int p = idx >> 20;          // 4096*256 = 2^20
        int e = idx & 1048575;
        int k = e >> 8;             // 0..4095
        int n = e & 255;
        const float* src = p ? w1i : w1u;
        float v = src[e];           // row-major [D][H]
        int kt  = k >> 6;
        int kbl = (k >> 3) & 7;
        int j   = k & 7;
        int dst = ((kt * 8 + kbl) * 256 + n) * 8 + j;
        ws[p * W1_STRIDE + dst] = f2bf(v);
    } else {
        int e2 = idx - 2 * DDIM * HDIM;   // 0..32767
        int p  = e2 >> 14;
        int e  = e2 & 16383;
        int k  = e >> 6;            // 0..255
        int n  = e & 63;
        const float* src = p ? w2i : w2u;
        float v = src[e];           // row-major [H][O]
        int dst = ((k >> 3) * 64 + n) * 8 + (k & 7);
        ws[OFF_W2 + p * W2_STRIDE + dst] = f2bf(v);
    }
}

// ---------------------------------------------------------------------------
// gemm1 v2: h = relu(x @ w1 + b1), bf16 MFMA.
// grid: 1024 blocks (512 row-blocks x 2 paths), 256 threads (4 waves).
// Row-split waves: wave w owns rows rb*64 + w*16 .. +15, ALL 256 cols.
//   -> A-frags load straight from global x into regs (fragment-native
//      pattern: lane(m15,q) reads 8 consecutive fp32), prefetched 1 kt ahead.
// w1 staged in LDS, double-buffered, global_load_lds width=16, prefetched
// 1 kt ahead. ONE barrier per kt; its vmcnt(0) drain waits on loads issued
// a full iteration earlier.
// LDS: 2 x [kb=8][n=256][8] bf16 = 64 KB -> 2 blocks/CU.
// ---------------------------------------------------------------------------
__global__ __launch_bounds__(256, 2) void gemm1_kernel(
    const float* __restrict__ xu, const float* __restrict__ xi,
    const float* __restrict__ b1u, const float* __restrict__ b1i,
    const unsigned short* __restrict__ w1_base,
    unsigned short* __restrict__ h_base)
{
    __shared__ unsigned short wls[2 * 8 * 256 * 8];   // 64 KB

    const int t    = threadIdx.x;
    const int lane = t & 63;
    const int w    = t >> 6;            // wave id = row-block within tile
    const int path = blockIdx.x & 1;
    const int rb   = blockIdx.x >> 1;   // 0..511
    const int m15  = lane & 15;
    const int q    = lane >> 4;

    const float* x  = path ? xi : xu;
    const float* b1 = path ? b1i : b1u;
    const unsigned short* wsw = w1_base + path * W1_STRIDE;
    unsigned short* hp = h_base + path * H_STRIDE;

    // This lane's x row and k-phase (A-frag native: 8 consecutive fp32)
    const int row = rb * 64 + w * 16 + m15;
    const float* xp = x + (size_t)row * DDIM + q * 8;

    f32x4 acc[16];
    #pragma unroll
    for (int nt = 0; nt < 16; ++nt)
        acc[nt] = (f32x4){0.f, 0.f, 0.f, 0.f};

    // ---- prologue: stage w(kt=0) into buf0; prefetch x(kt=0) into regs ----
    {
        const unsigned short* wsrc = wsw + t * 8;   // kt=0
        #pragma unroll
        for (int j = 0; j < 8; ++j) {
            __builtin_amdgcn_global_load_lds(
                (const __attribute__((address_space(1))) unsigned int*)(wsrc + j * 2048),
                (__attribute__((address_space(3))) unsigned int*)
                    ((char*)wls + (t & 192) * 16 + j * 4096),
                16, 0, 0);
        }
    }
    f32x4 xa0 = ((const f32x4*)(xp     ))[0];
    f32x4 xa1 = ((const f32x4*)(xp     ))[1];
    f32x4 xa2 = ((const f32x4*)(xp + 32))[0];
    f32x4 xa3 = ((const f32x4*)(xp + 32))[1];

    for (int kt = 0; kt < 64; ++kt) {
        // drain this thread's staging (issued last iter) + barrier:
        // buf[kt&1] is now valid, buf[(kt+1)&1] is free to overwrite.
        __syncthreads();

        const int ktn = (kt + 1) & 63;   // wrap: harmless redundant prefetch

        // ---- prefetch w(kt+1) into the other buffer (async, no wait) ----
        {
            const unsigned short* wsrc = wsw + ktn * 16384 + t * 8;
            char* dst = (char*)wls + ((kt + 1) & 1) * 32768 + (t & 192) * 16;
            #pragma unroll
            for (int j = 0; j < 8; ++j) {
                __builtin_amdgcn_global_load_lds(
                    (const __attribute__((address_space(1))) unsigned int*)(wsrc + j * 2048),
                    (__attribute__((address_space(3))) unsigned int*)(dst + j * 4096),
                    16, 0, 0);
            }
        }

        // ---- convert current x regs -> A-frags ----
        bf16x8 a0, a1;
        a0[0] = (short)f2bf(xa0[0]); a0[1] = (short)f2bf(xa0[1]);
        a0[2] = (short)f2bf(xa0[2]); a0[3] = (short)f2bf(xa0[3]);
        a0[4] = (short)f2bf(xa1[0]); a0[5] = (short)f2bf(xa1[1]);
        a0[6] = (short)f2bf(xa1[2]); a0[7] = (short)f2bf(xa1[3]);
        a1[0] = (short)f2bf(xa2[0]); a1[1] = (short)f2bf(xa2[1]);
        a1[2] = (short)f2bf(xa2[2]); a1[3] = (short)f2bf(xa2[3]);
        a1[4] = (short)f2bf(xa3[0]); a1[5] = (short)f2bf(xa3[1]);
        a1[6] = (short)f2bf(xa3[2]); a1[7] = (short)f2bf(xa3[3]);

        // ---- prefetch x(kt+1) into regs (async, consumed next iter) ----
        {
            const float* xn = xp + ktn * 64;
            xa0 = ((const f32x4*)(xn     ))[0];
            xa1 = ((const f32x4*)(xn     ))[1];
            xa2 = ((const f32x4*)(xn + 32))[0];
            xa3 = ((const f32x4*)(xn + 32))[1];
        }

        // ---- compute: 2 k-steps x 16 col-tiles ----
        const unsigned short* wb = wls + (kt & 1) * 16384;
        #pragma unroll
        for (int ks = 0; ks < 2; ++ks) {
            const bf16x8 a = ks ? a1 : a0;
            const int kbq = ks * 4 + q;
            #pragma unroll
            for (int nt = 0; nt < 16; ++nt) {
                bf16x8 b = *(const bf16x8*)&wb[kbq * 2048 + (nt * 16 + m15) * 8];
                acc[nt] = __builtin_amdgcn_mfma_f32_16x16x32_bf16(a, b, acc[nt], 0, 0, 0);
            }
        }
    }

    // ---- epilogue: +b1, relu, bf16 store (h row-major [32768][256]) ----
    #pragma unroll
    for (int nt = 0; nt < 16; ++nt) {
        const float bb = b1[nt * 16 + m15];
        const int r0 = rb * 64 + w * 16 + q * 4;
        #pragma unroll
        for (int r = 0; r < 4; ++r) {
            float v = acc[nt][r] + bb;
            v = fmaxf(v, 0.0f);
            hp[(size_t)(r0 + r) * HDIM + nt * 16 + m15] = f2bf(v);
        }
    }
}

// ---------------------------------------------------------------------------
// final: u = h_u @ w2u + b2u ; v = h_i @ w2i + b2i ; out = sigmoid(dot(u,v))
// grid: 512 blocks x 256 threads (4 waves, 16 rows/wave). No LDS.
// ---------------------------------------------------------------------------
__global__ __launch_bounds__(256) void final_kernel(
    const unsigned short* __restrict__ h_base,
    const unsigned short* __restrict__ w2_base,
    const float* __restrict__ b2u, const float* __restrict__ b2i,
    float* __restrict__ out)
{
    const int t    = threadIdx.x;
    const int lane = t & 63;
    const int w    = t >> 6;
    const int r0   = blockIdx.x * 64 + w * 16;
    const int m15  = lane & 15;
    const int q    = lane >> 4;

    f32x4 uacc[4], vacc[4];

    for (int path = 0; path < 2; ++path) {
        const unsigned short* h  = h_base  + path * H_STRIDE;
        const unsigned short* w2 = w2_base + path * W2_STRIDE;
        const float* b2 = path ? b2i : b2u;

        f32x4 acc[4];
        #pragma unroll
        for (int nt = 0; nt < 4; ++nt) acc[nt] = (f32x4){0.f, 0.f, 0.f, 0.f};

        #pragma unroll
        for (int ks = 0; ks < 8; ++ks) {
            const int kb = ks * 4 + q;
            bf16x8 a = *(const bf16x8*)&h[(size_t)(r0 + m15) * HDIM + kb * 8];
            #pragma unroll
            for (int nt = 0; nt < 4; ++nt) {
                bf16x8 b = *(const bf16x8*)&w2[(kb * 64 + nt * 16 + m15) * 8];
                acc[nt] = __builtin_amdgcn_mfma_f32_16x16x32_bf16(a, b, acc[nt], 0, 0, 0);
            }
        }
        #pragma unroll
        for (int nt = 0; nt < 4; ++nt) {
            const float bb = b2[nt * 16 + m15];
            #pragma unroll
            for (int r = 0; r < 4; ++r) acc[nt][r] += bb;
            if (path == 0) uacc[nt] = acc[nt]; else vacc[nt] = acc[nt];
        }
    }

    #pragma unroll
    for (int r = 0; r < 4; ++r) {
        float p = uacc[0][r] * vacc[0][r] + uacc[1][r] * vacc[1][r]
                + uacc[2][r] * vacc[2][r] + uacc[3][r] * vacc[3][r];
        p += __shfl_xor(p, 1);
        p += __shfl_xor(p, 2);
        p += __shfl_xor(p, 4);
        p += __shfl_xor(p, 8);
        if (m15 == 0)
            out[r0 + q * 4 + r] = 1.0f / (1.0f + __expf(-p));
    }
}

// ---------------------------------------------------------------------------
extern "C" void kernel_launch(void* const* d_in, const int* in_sizes, int n_in,
                              void* d_out, int out_size, void* d_ws, size_t ws_size,
                              hipStream_t stream)
{
    const float* xu  = (const float*)d_in[0];
    const float* xi  = (const float*)d_in[1];
    const float* w1u = (const float*)d_in[2];
    const float* b1u = (const float*)d_in[3];
    const float* w2u = (const float*)d_in[4];
    const float* b2u = (const float*)d_in[5];
    const float* w1i = (const float*)d_in[6];
    const float* b1i = (const float*)d_in[7];
    const float* w2i = (const float*)d_in[8];
    const float* b2i = (const float*)d_in[9];

    unsigned short* ws = (unsigned short*)d_ws;
    float* out = (float*)d_out;

    prep_kernel<<<8320, 256, 0, stream>>>(w1u, w1i, w2u, w2i, ws);

    gemm1_kernel<<<1024, 256, 0, stream>>>(xu, xi, b1u, b1i,
                                           ws, ws + OFF_H);

    final_kernel<<<512, 256, 0, stream>>>(ws + OFF_H, ws + OFF_W2,
                                          b2u, b2i, out);
}